// Round 2
// 176.944 us; speedup vs baseline: 1.0242x; 1.0242x over previous
//
#include <hip/hip_runtime.h>
#include <cstddef>

// Sizes (fixed per reference): B=8192, D=784, H=256, E=32, K=512
#define NB 8192
#define ND 784
#define NH 256
#define NE 32
#define NK 512
#define ALPHA_F 1000.0f

typedef _Float16 h8 __attribute__((ext_vector_type(8)));
typedef float f32x4 __attribute__((ext_vector_type(4)));

// ---------------------------------------------------------------------------
// Merged weight split+transpose: W [K][N] fp32 -> WT hi/lo [N][K] fp16.
// blocks 0..NH-1: W1 (K=ND); blocks NH..NH+ND-1: W4 (K=NH).
// ---------------------------------------------------------------------------
__global__ __launch_bounds__(256)
void splitw2_kernel(const float* __restrict__ W1, _Float16* __restrict__ w1thi,
                    _Float16* __restrict__ w1tlo,
                    const float* __restrict__ W4, _Float16* __restrict__ w4thi,
                    _Float16* __restrict__ w4tlo) {
    const int b = blockIdx.x;
    const float* W; _Float16 *hi, *lo; int K, N, n;
    if (b < NH) { W = W1; hi = w1thi; lo = w1tlo; K = ND; N = NH; n = b; }
    else        { W = W4; hi = w4thi; lo = w4tlo; K = NH; N = ND; n = b - NH; }
    for (int k = threadIdx.x; k < K; k += 256) {
        float w = W[(size_t)k * N + n];
        _Float16 hh = (_Float16)w;
        float r = w - (float)hh;
        hi[(size_t)n * K + k] = hh;
        lo[(size_t)n * K + k] = (_Float16)(r * 2048.0f);
    }
}

// ---------------------------------------------------------------------------
// MFMA split-fp16 GEMM body (same schedule as the verified mfma_gemm3):
// 256 threads (4 waves, 2x2 wave grid), BK=32, BN=64, BM=MT*32, double-
// buffered LDS, one barrier/step. __device__ body so the fused tail kernel
// can call it.
// ---------------------------------------------------------------------------
template<int TERMS, bool RELU, bool SPLITA, int MT>
__device__ __forceinline__ void gemm_body(
    const float* __restrict__ Af32,
    const _Float16* __restrict__ Ahi_g,
    const _Float16* __restrict__ Alo_g,
    const _Float16* __restrict__ WThi,
    const _Float16* __restrict__ WTlo,
    const float* __restrict__ bias, float* __restrict__ C,
    int N, int K, int KS, int bx, int by, int tid,
    _Float16* __restrict__ sAhi, _Float16* __restrict__ sAlo,
    _Float16* __restrict__ sBhi, _Float16* __restrict__ sBlo) {
    constexpr int BM  = MT * 32;
    constexpr int ACH = BM / 64;          // h8 chunks per thread per A plane
    constexpr int AS  = BM * 40;          // halves per A buffer
    constexpr int BS  = 64 * 40;          // halves per B buffer

    const int bm = bx * BM;
    const int bn = by * 64;

    const int arow = (ACH == 1) ? (tid >> 2) : (tid >> 1);
    const int ak   = (ACH == 1) ? ((tid & 3) * 8) : ((tid & 1) * 16);
    const int brow = tid >> 2;
    const int bk   = (tid & 3) * 8;

    const float*    pA32 = SPLITA ? Af32 + (size_t)(bm + arow) * K : nullptr;
    const _Float16* pAhi = SPLITA ? nullptr : Ahi_g + (size_t)(bm + arow) * K;
    const _Float16* pAlo = SPLITA ? nullptr : Alo_g + (size_t)(bm + arow) * K;
    int brow_g = bn + brow; if (brow_g > N - 1) brow_g = N - 1;  // N-edge tile
    const _Float16* pBhi = WThi + (size_t)brow_g * K;
    const _Float16* pBlo = WTlo + (size_t)brow_g * K;

    float araw[ACH * 8];
    h8 rahi[ACH], ralo[ACH];
    h8 rbhi, rblo;

    auto prefetch = [&](int s) {
        #pragma unroll
        for (int c = 0; c < ACH; ++c) {
            const int k = s * 32 + ak + c * 8;
            if (SPLITA) {
                if (k + 8 <= K) {
                    f32x4 v0 = *(const f32x4*)(pA32 + k);
                    f32x4 v1 = *(const f32x4*)(pA32 + k + 4);
                    #pragma unroll
                    for (int j = 0; j < 4; ++j) {
                        araw[c * 8 + j]     = v0[j];
                        araw[c * 8 + 4 + j] = v1[j];
                    }
                } else {
                    #pragma unroll
                    for (int j = 0; j < 8; ++j) araw[c * 8 + j] = 0.f;
                }
            } else {
                rahi[c] = (k + 8 <= K) ? *(const h8*)(pAhi + k) : (h8){};
                ralo[c] = (k + 8 <= K) ? *(const h8*)(pAlo + k) : (h8){};
            }
        }
        const int kb = s * 32 + bk;
        rbhi = (kb + 8 <= K) ? *(const h8*)(pBhi + kb) : (h8){};
        rblo = (kb + 8 <= K) ? *(const h8*)(pBlo + kb) : (h8){};
    };

    auto commit = [&](int buf) {
        #pragma unroll
        for (int c = 0; c < ACH; ++c) {
            h8 hi, lo;
            if (SPLITA) {
                #pragma unroll
                for (int j = 0; j < 8; ++j) {
                    float v = araw[c * 8 + j];
                    _Float16 hh = (_Float16)v;
                    hi[j] = hh;
                    lo[j] = (_Float16)((v - (float)hh) * 2048.0f);
                }
            } else { hi = rahi[c]; lo = ralo[c]; }
            *(h8*)&sAhi[buf * AS + arow * 40 + ak + c * 8] = hi;
            *(h8*)&sAlo[buf * AS + arow * 40 + ak + c * 8] = lo;
        }
        *(h8*)&sBhi[buf * BS + brow * 40 + bk] = rbhi;
        *(h8*)&sBlo[buf * BS + brow * 40 + bk] = rblo;
    };

    prefetch(0);
    commit(0);
    prefetch(1);
    __syncthreads();

    const int lane = tid & 63;
    const int wv   = tid >> 6;
    const int wm   = (wv >> 1) * (MT * 16);
    const int wn   = (wv & 1) * 32;
    const int li   = lane & 15;
    const int kq   = (lane >> 4) * 8;

    f32x4 acc0[MT][2] = {};
    f32x4 acc1[MT][2] = {};
    f32x4 acc2[MT][2] = {};

    for (int s = 0; s < KS; ++s) {
        const int buf = s & 1;
        h8 fahi[MT], falo[MT], fbhi[2], fblo[2];
        #pragma unroll
        for (int mt = 0; mt < MT; ++mt) {
            const int ao = buf * AS + (wm + mt * 16 + li) * 40 + kq;
            fahi[mt] = *(const h8*)&sAhi[ao];
            falo[mt] = *(const h8*)&sAlo[ao];
        }
        #pragma unroll
        for (int nt = 0; nt < 2; ++nt) {
            const int bo = buf * BS + (wn + nt * 16 + li) * 40 + kq;
            fbhi[nt] = *(const h8*)&sBhi[bo];
            fblo[nt] = *(const h8*)&sBlo[bo];
        }
        #pragma unroll
        for (int mt = 0; mt < MT; ++mt)
            #pragma unroll
            for (int nt = 0; nt < 2; ++nt) {
                acc0[mt][nt] = __builtin_amdgcn_mfma_f32_16x16x32_f16(
                    fahi[mt], fbhi[nt], acc0[mt][nt], 0, 0, 0);
                acc1[mt][nt] = __builtin_amdgcn_mfma_f32_16x16x32_f16(
                    fahi[mt], fblo[nt], acc1[mt][nt], 0, 0, 0);
                acc1[mt][nt] = __builtin_amdgcn_mfma_f32_16x16x32_f16(
                    falo[mt], fbhi[nt], acc1[mt][nt], 0, 0, 0);
                if (TERMS == 4)
                    acc2[mt][nt] = __builtin_amdgcn_mfma_f32_16x16x32_f16(
                        falo[mt], fblo[nt], acc2[mt][nt], 0, 0, 0);
            }
        if (s + 1 < KS) {
            commit((s + 1) & 1);
            if (s + 2 < KS) prefetch(s + 2);
        }
        __syncthreads();
    }

    const float c1 = 1.0f / 2048.0f;
    const float c2 = c1 * c1;
    const int quad = lane >> 4;
    #pragma unroll
    for (int nt = 0; nt < 2; ++nt) {
        const int n = bn + wn + nt * 16 + li;
        if (n < N) {
            const float bv = bias[n];
            #pragma unroll
            for (int mt = 0; mt < MT; ++mt) {
                #pragma unroll
                for (int r = 0; r < 4; ++r) {
                    const int m = bm + wm + mt * 16 + quad * 4 + r;
                    float v = acc0[mt][nt][r] + c1 * acc1[mt][nt][r];
                    if (TERMS == 4) v += c2 * acc2[mt][nt][r];
                    v += bv;
                    if (RELU) v = fmaxf(v, 0.f);
                    C[(size_t)m * N + n] = v;
                }
            }
        }
    }
}

// standalone wrapper (gemm1 in both paths, gemm4 in fallback path)
template<int TERMS, bool RELU, bool SPLITA, int MT>
__global__ __launch_bounds__(256)
void mfma_gemm3(const float* __restrict__ Af32,
                const _Float16* __restrict__ Ahi_g,
                const _Float16* __restrict__ Alo_g,
                const _Float16* __restrict__ WThi,
                const _Float16* __restrict__ WTlo,
                const float* __restrict__ bias, float* __restrict__ C,
                int N, int K, int KS) {
    constexpr int BM = MT * 32;
    __shared__ __align__(16) _Float16 smem[2 * BM * 40 * 2 + 2 * 64 * 40 * 2];
    _Float16* sAhi = smem;
    _Float16* sAlo = sAhi + 2 * BM * 40;
    _Float16* sBhi = sAlo + 2 * BM * 40;
    _Float16* sBlo = sBhi + 2 * 64 * 40;
    gemm_body<TERMS, RELU, SPLITA, MT>(Af32, Ahi_g, Alo_g, WThi, WTlo, bias, C,
                                       N, K, KS, blockIdx.x, blockIdx.y,
                                       threadIdx.x, sAhi, sAlo, sBhi, sBlo);
}

// ---------------------------------------------------------------------------
// Fused: emb[B,32] = h@W2+b2 (fp32); h2 = relu(emb@W3+b3) as fp16 hi/lo.
// ---------------------------------------------------------------------------
__global__ __launch_bounds__(256)
void mid_kernel(const float* __restrict__ h, const float* __restrict__ W2,
                const float* __restrict__ b2, const float* __restrict__ W3,
                const float* __restrict__ b3, float* __restrict__ emb,
                _Float16* __restrict__ h2hi, _Float16* __restrict__ h2lo) {
    __shared__ float es[16][32];
    const int tid = threadIdx.x;
    const int r0  = blockIdx.x * 16;

    #pragma unroll
    for (int half = 0; half < 2; ++half) {
        const int o   = tid + half * 256;
        const int row = o >> 5;
        const int col = o & 31;
        const float* hrow = h + (size_t)(r0 + row) * NH;
        float acc0 = 0.f, acc1 = 0.f;
        #pragma unroll 4
        for (int k = 0; k < NH; k += 4) {
            float4 hv = *(const float4*)(hrow + k);
            acc0 = fmaf(hv.x, W2[(k + 0) * NE + col], acc0);
            acc1 = fmaf(hv.y, W2[(k + 1) * NE + col], acc1);
            acc0 = fmaf(hv.z, W2[(k + 2) * NE + col], acc0);
            acc1 = fmaf(hv.w, W2[(k + 3) * NE + col], acc1);
        }
        float v = acc0 + acc1 + b2[col];
        es[row][col] = v;
        emb[(size_t)r0 * NE + o] = v;
    }
    __syncthreads();

    const int col = tid;
    float acc[16];
    #pragma unroll
    for (int r = 0; r < 16; ++r) acc[r] = 0.f;
    #pragma unroll
    for (int k = 0; k < NE; ++k) {
        float w = W3[k * NH + col];
        #pragma unroll
        for (int r = 0; r < 16; ++r) acc[r] = fmaf(es[r][k], w, acc[r]);
    }
    const float bb = b3[col];
    #pragma unroll
    for (int r = 0; r < 16; ++r) {
        float v = acc[r] + bb;
        v = v > 0.f ? v : 0.f;
        _Float16 hh = (_Float16)v;
        float rr = v - (float)hh;
        h2hi[(size_t)(r0 + r) * NH + col] = hh;
        h2lo[(size_t)(r0 + r) * NH + col] = (_Float16)(rr * 2048.0f);
    }
}

// ---------------------------------------------------------------------------
// dist body, 256 threads: block handles 8 rows; thread owns clusters tid and
// tid+256. Same padded-LDS transpose + shuffle reductions as the verified
// 512-thread version; 4 waves each reduce rows {wv, wv+4}.
// ---------------------------------------------------------------------------
__device__ __forceinline__ void dist_body256(
    const float* __restrict__ emb, const float* __restrict__ reps,
    float* __restrict__ dist, float* __restrict__ wout,
    int blk, int tid, float* __restrict__ es, float* __restrict__ tr,
    float* __restrict__ rmin, float* __restrict__ rinv) {
    const int r0 = blk * 8;
    es[tid] = emb[(size_t)r0 * NE + tid];   // es flat [8*32]

    const float* rp0 = reps + (size_t)tid * NE;
    const float* rp1 = reps + (size_t)(tid + 256) * NE;
    f32x4 rv0[8], rv1[8];
    #pragma unroll
    for (int e4 = 0; e4 < 8; ++e4) {
        rv0[e4] = ((const f32x4*)rp0)[e4];
        rv1[e4] = ((const f32x4*)rp1)[e4];
    }
    __syncthreads();

    float d0[8], d1[8];
    #pragma unroll
    for (int r = 0; r < 8; ++r) {
        float a0 = 0.f, a1 = 0.f;
        #pragma unroll
        for (int e4 = 0; e4 < 8; ++e4) {
            f32x4 ev = *(const f32x4*)&es[r * 32 + e4 * 4];
            #pragma unroll
            for (int j = 0; j < 4; ++j) {
                float t0 = ev[j] - rv0[e4][j];
                a0 = fmaf(t0, t0, a0);
                float t1 = ev[j] - rv1[e4][j];
                a1 = fmaf(t1, t1, a1);
            }
        }
        d0[r] = a0; d1[r] = a1;
    }

    const int lane = tid & 63;
    const int wv   = tid >> 6;

    #pragma unroll
    for (int r = 0; r < 8; ++r) {
        tr[r * 520 + tid]       = d0[r];
        tr[r * 520 + 256 + tid] = d1[r];
    }
    __syncthreads();
    #pragma unroll
    for (int p = 0; p < 2; ++p) {
        const int rr = wv + p * 4;
        f32x4 a = *(const f32x4*)&tr[rr * 520 + lane * 8];
        f32x4 b = *(const f32x4*)&tr[rr * 520 + lane * 8 + 4];
        float m = fminf(fminf(fminf(a[0], a[1]), fminf(a[2], a[3])),
                        fminf(fminf(b[0], b[1]), fminf(b[2], b[3])));
        #pragma unroll
        for (int off = 32; off > 0; off >>= 1)
            m = fminf(m, __shfl_xor(m, off, 64));
        if (lane == 0) rmin[rr] = m;
    }
    __syncthreads();

    float e0[8], e1[8];
    #pragma unroll
    for (int r = 0; r < 8; ++r) {
        e0[r] = expf(-ALPHA_F * (d0[r] - rmin[r]));
        e1[r] = expf(-ALPHA_F * (d1[r] - rmin[r]));
        tr[r * 520 + tid]       = e0[r];
        tr[r * 520 + 256 + tid] = e1[r];
    }
    __syncthreads();
    #pragma unroll
    for (int p = 0; p < 2; ++p) {
        const int rr = wv + p * 4;
        f32x4 a = *(const f32x4*)&tr[rr * 520 + lane * 8];
        f32x4 b = *(const f32x4*)&tr[rr * 520 + lane * 8 + 4];
        float s = ((a[0] + a[1]) + (a[2] + a[3])) +
                  ((b[0] + b[1]) + (b[2] + b[3]));
        #pragma unroll
        for (int off = 32; off > 0; off >>= 1)
            s += __shfl_xor(s, off, 64);
        if (lane == 0) rinv[rr] = 1.0f / s;
    }
    __syncthreads();

    #pragma unroll
    for (int r = 0; r < 8; ++r) {
        const size_t row = (size_t)(r0 + r);
        dist[row * NK + tid]       = d0[r];
        dist[row * NK + 256 + tid] = d1[r];
        wout[row * NK + tid]       = d0[r] * (e0[r] * rinv[r]);
        wout[row * NK + 256 + tid] = d1[r] * (e1[r] * rinv[r]);
    }
}

// 512-thread standalone dist (fallback path only) — original verified code.
__global__ __launch_bounds__(512, 4)
void dist_kernel(const float* __restrict__ emb, const float* __restrict__ reps,
                 float* __restrict__ dist, float* __restrict__ wout) {
    __shared__ float es[8][32];
    __shared__ float tr[8][520];
    __shared__ float rmin[8];
    __shared__ float rinv[8];

    const int tid = threadIdx.x;
    const int r0  = blockIdx.x * 8;

    if (tid < 256) es[tid >> 5][tid & 31] = emb[(size_t)r0 * NE + tid];

    const float* rp = reps + (size_t)tid * NE;
    f32x4 rv[8];
    #pragma unroll
    for (int e4 = 0; e4 < 8; ++e4) rv[e4] = ((const f32x4*)rp)[e4];
    __syncthreads();

    float d[8];
    #pragma unroll
    for (int r = 0; r < 8; ++r) {
        float a = 0.f;
        #pragma unroll
        for (int e4 = 0; e4 < 8; ++e4) {
            f32x4 ev = *(const f32x4*)&es[r][e4 * 4];
            #pragma unroll
            for (int j = 0; j < 4; ++j) {
                float t = ev[j] - rv[e4][j];
                a = fmaf(t, t, a);
            }
        }
        d[r] = a;
    }

    const int lane = tid & 63;
    const int wv   = tid >> 6;

    #pragma unroll
    for (int r = 0; r < 8; ++r) tr[r][tid] = d[r];
    __syncthreads();
    {
        f32x4 a = *(const f32x4*)&tr[wv][lane * 8];
        f32x4 b = *(const f32x4*)&tr[wv][lane * 8 + 4];
        float m = fminf(fminf(fminf(a[0], a[1]), fminf(a[2], a[3])),
                        fminf(fminf(b[0], b[1]), fminf(b[2], b[3])));
        #pragma unroll
        for (int off = 32; off > 0; off >>= 1)
            m = fminf(m, __shfl_xor(m, off, 64));
        if (lane == 0) rmin[wv] = m;
    }
    __syncthreads();

    float e[8];
    #pragma unroll
    for (int r = 0; r < 8; ++r) {
        e[r] = expf(-ALPHA_F * (d[r] - rmin[r]));
        tr[r][tid] = e[r];
    }
    __syncthreads();
    {
        f32x4 a = *(const f32x4*)&tr[wv][lane * 8];
        f32x4 b = *(const f32x4*)&tr[wv][lane * 8 + 4];
        float s = ((a[0] + a[1]) + (a[2] + a[3])) +
                  ((b[0] + b[1]) + (b[2] + b[3]));
        #pragma unroll
        for (int off = 32; off > 0; off >>= 1)
            s += __shfl_xor(s, off, 64);
        if (lane == 0) rinv[wv] = 1.0f / s;
    }
    __syncthreads();

    #pragma unroll
    for (int r = 0; r < 8; ++r) {
        const size_t row = (size_t)(r0 + r);
        dist[row * NK + tid] = d[r];
        wout[row * NK + tid] = d[r] * (e[r] * rinv[r]);
    }
}

// ---------------------------------------------------------------------------
// Fused tail: gemm4 (recon = h2 @ W4 + b4) and dist+softmin are independent
// given mid's outputs — run both in ONE launch, block-specialized and 1:1
// interleaved so each CU hosts one MFMA-bound block and one HBM-write-bound
// block. 256 threads everywhere; LDS = max(gemm4 61.4KB, dist 17.7KB) -> 2
// blocks/CU. Requires h2/W4T scratch OUTSIDE the dist/wout outputs (d_ws).
// ---------------------------------------------------------------------------
#define NGB (64 * 13)   // 832 gemm4 blocks (bx=idx&63, by=idx>>6)
#define NDB (NB / 8)    // 1024 dist blocks

__global__ __launch_bounds__(256)
void tail_fused(const _Float16* __restrict__ h2hi,
                const _Float16* __restrict__ h2lo,
                const _Float16* __restrict__ w4thi,
                const _Float16* __restrict__ w4tlo,
                const float* __restrict__ b4, float* __restrict__ recon,
                const float* __restrict__ emb, const float* __restrict__ reps,
                float* __restrict__ dist, float* __restrict__ wout) {
    __shared__ __align__(16) _Float16 smem[2 * 128 * 40 * 2 + 2 * 64 * 40 * 2];
    const int bid = blockIdx.x;
    const int tid = threadIdx.x;

    bool isDist; int idx;
    if (bid < 2 * NGB) { isDist = (bid & 1); idx = bid >> 1; }
    else               { isDist = true; idx = NGB + (bid - 2 * NGB); }

    if (!isDist) {
        _Float16* sAhi = smem;
        _Float16* sAlo = sAhi + 2 * 128 * 40;
        _Float16* sBhi = sAlo + 2 * 128 * 40;
        _Float16* sBlo = sBhi + 2 * 64 * 40;
        gemm_body<3, false, false, 4>(nullptr, h2hi, h2lo, w4thi, w4tlo, b4,
                                      recon, ND, NH, 8, idx & 63, idx >> 6,
                                      tid, sAhi, sAlo, sBhi, sBlo);
    } else {
        float* es   = (float*)smem;          // [8*32]
        float* tr   = es + 8 * 32;           // [8*520]
        float* rmin = tr + 8 * 520;          // [8]
        float* rinv = rmin + 8;              // [8]
        dist_body256(emb, reps, dist, wout, idx, tid, es, tr, rmin, rinv);
    }
}

// ---------------------------------------------------------------------------
extern "C" void kernel_launch(void* const* d_in, const int* in_sizes, int n_in,
                              void* d_out, int out_size, void* d_ws, size_t ws_size,
                              hipStream_t stream) {
    const float* x    = (const float*)d_in[0];
    const float* reps = (const float*)d_in[1];
    const float* W1   = (const float*)d_in[2];
    const float* b1   = (const float*)d_in[3];
    const float* W2   = (const float*)d_in[4];
    const float* b2   = (const float*)d_in[5];
    const float* W3   = (const float*)d_in[6];
    const float* b3   = (const float*)d_in[7];
    const float* W4   = (const float*)d_in[8];
    const float* b4   = (const float*)d_in[9];

    float* out   = (float*)d_out;
    float* wout  = out;                                          // [8192,512]
    float* dist  = out + (size_t)NB * NK;                        // [8192,512]
    float* recon = out + (size_t)2 * NB * NK;                    // [8192,784]
    float* emb   = out + (size_t)2 * NB * NK + (size_t)NB * ND;  // [8192,32]

    // h is dead before anything in the tail launch touches the dist region.
    float* h = dist;

    // Workspace need: W1T/W4T hi+lo planes + h2 hi/lo planes (these are READ
    // during the fused tail launch while dist blocks WRITE dist/wout, so they
    // must not alias the outputs).
    const size_t wneed = ((size_t)4 * ND * NH + (size_t)2 * NB * NH)
                         * sizeof(_Float16);   // ~9.6 MB

    if (d_ws != nullptr && ws_size >= wneed) {
        _Float16* w1thi = (_Float16*)d_ws;
        _Float16* w1tlo = w1thi + (size_t)NH * ND;
        _Float16* w4thi = w1tlo + (size_t)NH * ND;
        _Float16* w4tlo = w4thi + (size_t)ND * NH;
        _Float16* h2hi  = w4tlo + (size_t)ND * NH;
        _Float16* h2lo  = h2hi + (size_t)NB * NH;

        // 0) weight split+transpose
        splitw2_kernel<<<NH + ND, 256, 0, stream>>>(W1, w1thi, w1tlo,
                                                    W4, w4thi, w4tlo);
        // 1) h = relu(x @ W1 + b1)
        mfma_gemm3<4, true, true, 2><<<dim3(128, 4), 256, 0, stream>>>(
            x, nullptr, nullptr, w1thi, w1tlo, b1, h, NH, ND, 25);
        // 2) emb + h2 planes (to workspace)
        mid_kernel<<<NB / 16, 256, 0, stream>>>(h, W2, b2, W3, b3,
                                                emb, h2hi, h2lo);
        // 3+4) fused gemm4 + dist/softmin, 1:1 interleaved block order
        tail_fused<<<2 * NGB + (NDB - NGB), 256, 0, stream>>>(
            h2hi, h2lo, w4thi, w4tlo, b4, recon, emb, reps, dist, wout);
    } else {
        // Fallback: original serialized 5-launch path with output-aliased
        // scratch (safe because launches are ordered).
        _Float16* h2hi  = (_Float16*)(dist + (size_t)NB * NH);
        _Float16* h2lo  = h2hi + (size_t)NB * NH;
        _Float16* w1thi = (_Float16*)wout;
        _Float16* w1tlo = w1thi + (size_t)NH * ND;
        _Float16* w4thi = w1tlo + (size_t)NH * ND;
        _Float16* w4tlo = w4thi + (size_t)ND * NH;

        splitw2_kernel<<<NH + ND, 256, 0, stream>>>(W1, w1thi, w1tlo,
                                                    W4, w4thi, w4tlo);
        mfma_gemm3<4, true, true, 2><<<dim3(128, 4), 256, 0, stream>>>(
            x, nullptr, nullptr, w1thi, w1tlo, b1, h, NH, ND, 25);
        mid_kernel<<<NB / 16, 256, 0, stream>>>(h, W2, b2, W3, b3,
                                                emb, h2hi, h2lo);
        mfma_gemm3<3, false, false, 4><<<dim3(64, 13), 256, 0, stream>>>(
            nullptr, h2hi, h2lo, w4thi, w4tlo, b4, recon, ND, NH, 8);
        dist_kernel<<<NB / 8, 512, 0, stream>>>(emb, reps, dist, wout);
    }
}